// Round 9
// baseline (568.016 us; speedup 1.0000x reference)
//
#include <hip/hip_runtime.h>
#include <math.h>

#define B_ROWS 16384
#define DIM    256
#define K_CODES 4096

// d_out element offsets (f32), reference return order:
// z_q_st (16384x256), vq_loss (1), indices (16384),
// new_codebook (4096x256), new_cluster_size (4096), new_embed_sum (4096x256)
#define OUT_ZQ   0
#define OUT_LOSS 4194304
#define OUT_IDX  4194305
#define OUT_NCB  4210689
#define OUT_NCS  5259265
#define OUT_NES  5263361

// GEMM-argmin tiling
#define BM 128
#define BN 128
#define BK 16
#define TM 8
#define TN 8
#define NSPLIT 8
#define CODES_PER_SPLIT (K_CODES / NSPLIT)     // 512
#define CT_PER_SPLIT    (CODES_PER_SPLIT / BN) // 4

// ---------------------------------------------------------------------------
// numpy-faithful pairwise sum of squares for a 256-row (f32, no FMA contraction).
// numpy pairwise_sum(n=256): split 128+128; each 128: 8 accumulators over 16
// strided steps, combined ((r0+r1)+(r2+r3))+((r4+r5)+(r6+r7)); halves added.
// Must be bit-exact vs np.sum(x*x, axis=1): squares rounded, then added.
// ---------------------------------------------------------------------------
__device__ __forceinline__ float np_sumsq_row(const float* __restrict__ p) {
    float halves[2];
#pragma unroll
    for (int h = 0; h < 2; ++h) {
        const float* q = p + h * 128;
        float r[8];
        {
            float4 v0 = *(const float4*)(q);
            float4 v1 = *(const float4*)(q + 4);
            r[0] = __fmul_rn(v0.x, v0.x); r[1] = __fmul_rn(v0.y, v0.y);
            r[2] = __fmul_rn(v0.z, v0.z); r[3] = __fmul_rn(v0.w, v0.w);
            r[4] = __fmul_rn(v1.x, v1.x); r[5] = __fmul_rn(v1.y, v1.y);
            r[6] = __fmul_rn(v1.z, v1.z); r[7] = __fmul_rn(v1.w, v1.w);
        }
#pragma unroll
        for (int t = 1; t < 16; ++t) {
            float4 v0 = *(const float4*)(q + 8 * t);
            float4 v1 = *(const float4*)(q + 8 * t + 4);
            r[0] = __fadd_rn(r[0], __fmul_rn(v0.x, v0.x));
            r[1] = __fadd_rn(r[1], __fmul_rn(v0.y, v0.y));
            r[2] = __fadd_rn(r[2], __fmul_rn(v0.z, v0.z));
            r[3] = __fadd_rn(r[3], __fmul_rn(v0.w, v0.w));
            r[4] = __fadd_rn(r[4], __fmul_rn(v1.x, v1.x));
            r[5] = __fadd_rn(r[5], __fmul_rn(v1.y, v1.y));
            r[6] = __fadd_rn(r[6], __fmul_rn(v1.z, v1.z));
            r[7] = __fadd_rn(r[7], __fmul_rn(v1.w, v1.w));
        }
        const float s01 = __fadd_rn(r[0], r[1]);
        const float s23 = __fadd_rn(r[2], r[3]);
        const float s45 = __fadd_rn(r[4], r[5]);
        const float s67 = __fadd_rn(r[6], r[7]);
        halves[h] = __fadd_rn(__fadd_rn(s01, s23), __fadd_rn(s45, s67));
    }
    return __fadd_rn(halves[0], halves[1]);
}

// ---------------- row norms (codebook and z), numpy-faithful ----------------
__global__ void cnorm_kernel(const float* __restrict__ cb, float* __restrict__ cnorm) {
    const int row = blockIdx.x * 256 + threadIdx.x;
    if (row < K_CODES) cnorm[row] = np_sumsq_row(&cb[(size_t)row * DIM]);
}

__global__ void znorm_kernel(const float* __restrict__ z, float* __restrict__ znorm) {
    const int row = blockIdx.x * 256 + threadIdx.x;
    if (row < B_ROWS) znorm[row] = np_sumsq_row(&z[(size_t)row * DIM]);
}

// ---------------- fused GEMM + argmin (f32, vector ALU) ----------------
// Score replicates the reference's f32 rounding chain exactly:
//   s = fl( fl( znorm_b - fl(2*dot) ) + cnorm_k )
// at magnitude ~256 (ulp 2^-15) so quantized TIES match np.argmin's
// lowest-index resolution. Do NOT "optimize" the znorm term away: the
// tie structure depends on its exact bits.
__global__ __launch_bounds__(256) void argmin_kernel(
    const float* __restrict__ z, const float* __restrict__ cb,
    const float* __restrict__ cnorm, const float* __restrict__ znorm,
    float* __restrict__ pval, int* __restrict__ pidx)
{
    __shared__ float As[BK][BM + 4];
    __shared__ float Bs[BK][BN + 4];
    const int tid     = threadIdx.x;
    const int split   = blockIdx.x % NSPLIT;
    const int rowTile = blockIdx.x / NSPLIT;
    const int row0    = rowTile * BM;
    const int code0   = split * CODES_PER_SPLIT;
    const int tx = tid & 15;   // code sub-tile
    const int ty = tid >> 4;   // row sub-tile

    float best[TM];
    int   bestIdx[TM];
    float zn[TM];
#pragma unroll
    for (int i = 0; i < TM; ++i) {
        best[i] = 3.4028235e38f; bestIdx[i] = 0;
        zn[i] = znorm[row0 + ty * TM + i];
    }

    const int lm = tid >> 2;         // 0..63 (staging row)
    const int lk = (tid & 3) * 4;    // 0,4,8,12 (staging k)

    for (int ct = 0; ct < CT_PER_SPLIT; ++ct) {
        const int cbase = code0 + ct * BN;
        float acc[TM][TN];
#pragma unroll
        for (int i = 0; i < TM; ++i)
#pragma unroll
            for (int j = 0; j < TN; ++j) acc[i][j] = 0.f;

        for (int kt = 0; kt < DIM / BK; ++kt) {
#pragma unroll
            for (int p = 0; p < 2; ++p) {
                const int mm = lm + p * 64;
                const float4 av = *(const float4*)&z[(size_t)(row0 + mm) * DIM + kt * BK + lk];
                As[lk + 0][mm] = av.x; As[lk + 1][mm] = av.y;
                As[lk + 2][mm] = av.z; As[lk + 3][mm] = av.w;
                const float4 bv = *(const float4*)&cb[(size_t)(cbase + mm) * DIM + kt * BK + lk];
                Bs[lk + 0][mm] = bv.x; Bs[lk + 1][mm] = bv.y;
                Bs[lk + 2][mm] = bv.z; Bs[lk + 3][mm] = bv.w;
            }
            __syncthreads();
#pragma unroll
            for (int k = 0; k < BK; ++k) {
                float a[TM], b[TN];
#pragma unroll
                for (int i = 0; i < TM; ++i) a[i] = As[k][ty * TM + i];
#pragma unroll
                for (int j = 0; j < TN; ++j) b[j] = Bs[k][tx * TN + j];
#pragma unroll
                for (int i = 0; i < TM; ++i)
#pragma unroll
                    for (int j = 0; j < TN; ++j)
                        acc[i][j] = fmaf(a[i], b[j], acc[i][j]);
            }
            __syncthreads();
        }
        // epilogue: reference-faithful f32 chain; codes visited in increasing
        // order per thread; strict < keeps first (lowest-index) min.
#pragma unroll
        for (int j = 0; j < TN; ++j) {
            const int code = cbase + tx * TN + j;
            const float cn = cnorm[code];
#pragma unroll
            for (int i = 0; i < TM; ++i) {
                const float t = __fsub_rn(zn[i], __fmul_rn(2.0f, acc[i][j]));
                const float s = __fadd_rn(t, cn);
                if (s < best[i]) { best[i] = s; bestIdx[i] = code; }
            }
        }
    }
    // reduce across the 16 tx lanes (contiguous within wave); tie -> lower index
#pragma unroll
    for (int mask = 1; mask < 16; mask <<= 1) {
#pragma unroll
        for (int i = 0; i < TM; ++i) {
            const float ov = __shfl_xor(best[i], mask);
            const int   oi = __shfl_xor(bestIdx[i], mask);
            if (ov < best[i] || (ov == best[i] && oi < bestIdx[i])) { best[i] = ov; bestIdx[i] = oi; }
        }
    }
    if (tx == 0) {
#pragma unroll
        for (int i = 0; i < TM; ++i) {
            const int row = row0 + ty * TM + i;
            pval[(size_t)split * B_ROWS + row] = best[i];
            pidx[(size_t)split * B_ROWS + row] = bestIdx[i];
        }
    }
}

// ---------------- merge split partials ----------------
__global__ void merge_kernel(const float* __restrict__ pval, const int* __restrict__ pidx,
                             int* __restrict__ indices) {
    const int b = blockIdx.x * 256 + threadIdx.x;
    float bv = pval[b]; int bi = pidx[b];
#pragma unroll
    for (int s = 1; s < NSPLIT; ++s) {
        const float v  = pval[(size_t)s * B_ROWS + b];
        const int   i2 = pidx[(size_t)s * B_ROWS + b];
        if (v < bv || (v == bv && i2 < bi)) { bv = v; bi = i2; }
    }
    indices[b] = bi;
}

// ---------------- histogram ----------------
__global__ void count_kernel(const int* __restrict__ idx, int* __restrict__ counts) {
    const int b = blockIdx.x * 256 + threadIdx.x;
    atomicAdd(&counts[idx[b]], 1);
}

// ---------------- single-wave exclusive scan over 4096 counts ----------------
__global__ void scan_kernel(const int* __restrict__ counts, int* __restrict__ offsets,
                            int* __restrict__ cursor) {
    const int lane = threadIdx.x;   // 64 lanes
    const int base = lane * 64;
    int s = 0;
    for (int i = 0; i < 64; ++i) s += counts[base + i];
    int v = s;
#pragma unroll
    for (int d = 1; d < 64; d <<= 1) {
        const int o = __shfl_up(v, d);
        if (lane >= d) v += o;
    }
    int run = v - s;   // exclusive prefix of this lane's chunk
    for (int i = 0; i < 64; ++i) {
        const int c = counts[base + i];
        offsets[base + i] = run;
        cursor[base + i]  = run;
        run += c;
    }
}

// ---------------- bucket scatter ----------------
__global__ void scatter_kernel(const int* __restrict__ idx, int* __restrict__ cursor,
                               int* __restrict__ buckets) {
    const int b = blockIdx.x * 256 + threadIdx.x;
    const int pos = atomicAdd(&cursor[idx[b]], 1);
    buckets[pos] = b;
}

// ---------------- per-code EMA update ----------------
__global__ void update_kernel(const float* __restrict__ z,
                              const float* __restrict__ ema_es, const float* __restrict__ ema_cs,
                              const int* __restrict__ counts, const int* __restrict__ offsets,
                              const int* __restrict__ buckets,
                              float* __restrict__ out_nes, float* __restrict__ out_ncs,
                              float* __restrict__ ws_ncs) {
    const int k = blockIdx.x;
    const int d = threadIdx.x;
    const int c = counts[k];
    const int o = offsets[k];
    float acc = 0.f;
    for (int j = 0; j < c; ++j) {
        const int r = buckets[o + j];
        acc += z[(size_t)r * DIM + d];
    }
    out_nes[(size_t)k * DIM + d] = 0.99f * ema_es[(size_t)k * DIM + d] + 0.01f * acc;
    if (d == 0) {
        const float ncs = 0.99f * ema_cs[k] + 0.01f * (float)c;
        out_ncs[k] = ncs;
        ws_ncs[k]  = ncs;
    }
}

// ---------------- n = sum(new_cluster_size) ----------------
__global__ void nsum_kernel(const float* __restrict__ ws_ncs, float* __restrict__ ws_n) {
    __shared__ float red[256];
    const int tid = threadIdx.x;
    float s = 0.f;
    for (int i = tid; i < K_CODES; i += 256) s += ws_ncs[i];
    red[tid] = s; __syncthreads();
    for (int st = 128; st > 0; st >>= 1) {
        if (tid < st) red[tid] += red[tid + st];
        __syncthreads();
    }
    if (tid == 0) ws_n[0] = red[0];
}

// ---------------- new_codebook = new_embed_sum / cluster_size ----------------
__global__ void codebook_kernel(const float* __restrict__ out_nes, const float* __restrict__ ws_ncs,
                                const float* __restrict__ ws_n, float* __restrict__ out_ncb) {
    const int k = blockIdx.x;
    const int d = threadIdx.x;
    const float n = ws_n[0];
    const float cs = (ws_ncs[k] + 1e-5f) / (n + (float)K_CODES * 1e-5f) * n;
    out_ncb[(size_t)k * DIM + d] = out_nes[(size_t)k * DIM + d] / cs;
}

// ---------------- z_q gather + straight-through + loss ----------------
__global__ void gather_loss_kernel(const float* __restrict__ z, const float* __restrict__ cb,
                                   const int* __restrict__ idx,
                                   float* __restrict__ out_zq, float* __restrict__ out_loss) {
    __shared__ float red[256];
    const int tid = threadIdx.x;
    float acc = 0.f;
    for (size_t i = blockIdx.x * 256 + tid; i < (size_t)B_ROWS * DIM; i += (size_t)gridDim.x * 256) {
        const int b = (int)(i >> 8);
        const int d = (int)(i & 255);
        const int k = idx[b];
        const float zq = cb[(size_t)k * DIM + d];
        const float ze = z[i];
        out_zq[i] = __fadd_rn(ze, __fsub_rn(zq, ze));  // straight-through, literal f32 chain
        const float diff = zq - ze;
        acc += diff * diff;
    }
    red[tid] = acc; __syncthreads();
    for (int st = 128; st > 0; st >>= 1) {
        if (tid < st) red[tid] += red[tid + st];
        __syncthreads();
    }
    // 0.25 / (16384*256) = 2^-24, exact power of two
    if (tid == 0) atomicAdd(out_loss, red[0] * (0.25f / 4194304.0f));
}

// ---------------- indices as f32 output ----------------
__global__ void idx_out_kernel(const int* __restrict__ idx, float* __restrict__ out) {
    const int b = blockIdx.x * 256 + threadIdx.x;
    out[b] = (float)idx[b];
}

extern "C" void kernel_launch(void* const* d_in, const int* in_sizes, int n_in,
                              void* d_out, int out_size, void* d_ws, size_t ws_size,
                              hipStream_t stream) {
    const float* z      = (const float*)d_in[0];
    const float* cb     = (const float*)d_in[1];
    const float* ema_cs = (const float*)d_in[2];
    const float* ema_es = (const float*)d_in[3];
    float* out = (float*)d_out;

    char* p = (char*)d_ws;
    int*   indices = (int*)p;   p += B_ROWS * 4;
    int*   counts  = (int*)p;   p += K_CODES * 4;
    int*   offsets = (int*)p;   p += K_CODES * 4;
    int*   cursor  = (int*)p;   p += K_CODES * 4;
    int*   buckets = (int*)p;   p += B_ROWS * 4;
    float* cnorm   = (float*)p; p += K_CODES * 4;
    float* znorm   = (float*)p; p += B_ROWS * 4;
    float* ws_ncs  = (float*)p; p += K_CODES * 4;
    float* ws_n    = (float*)p; p += 256;         // padded
    float* pval    = (float*)p; p += (size_t)NSPLIT * B_ROWS * 4;
    int*   pidx    = (int*)p;   p += (size_t)NSPLIT * B_ROWS * 4;

    hipMemsetAsync(counts, 0, K_CODES * 4, stream);
    hipMemsetAsync(out + OUT_LOSS, 0, 4, stream);

    cnorm_kernel<<<(K_CODES + 255) / 256, 256, 0, stream>>>(cb, cnorm);
    znorm_kernel<<<(B_ROWS + 255) / 256, 256, 0, stream>>>(z, znorm);
    argmin_kernel<<<(B_ROWS / BM) * NSPLIT, 256, 0, stream>>>(z, cb, cnorm, znorm, pval, pidx);
    merge_kernel<<<B_ROWS / 256, 256, 0, stream>>>(pval, pidx, indices);
    count_kernel<<<B_ROWS / 256, 256, 0, stream>>>(indices, counts);
    scan_kernel<<<1, 64, 0, stream>>>(counts, offsets, cursor);
    scatter_kernel<<<B_ROWS / 256, 256, 0, stream>>>(indices, cursor, buckets);
    update_kernel<<<K_CODES, 256, 0, stream>>>(z, ema_es, ema_cs, counts, offsets, buckets,
                                               out + OUT_NES, out + OUT_NCS, ws_ncs);
    nsum_kernel<<<1, 256, 0, stream>>>(ws_ncs, ws_n);
    codebook_kernel<<<K_CODES, 256, 0, stream>>>(out + OUT_NES, ws_ncs, ws_n, out + OUT_NCB);
    gather_loss_kernel<<<1024, 256, 0, stream>>>(z, cb, indices, out + OUT_ZQ, out + OUT_LOSS);
    idx_out_kernel<<<B_ROWS / 256, 256, 0, stream>>>(indices, out + OUT_IDX);
}

// Round 10
// 451.754 us; speedup vs baseline: 1.2574x; 1.2574x over previous
//
#include <hip/hip_runtime.h>
#include <math.h>

#define B_ROWS 16384
#define DIM    256
#define K_CODES 4096

// d_out element offsets (f32), reference return order:
// z_q_st (16384x256), vq_loss (1), indices (16384),
// new_codebook (4096x256), new_cluster_size (4096), new_embed_sum (4096x256)
#define OUT_ZQ   0
#define OUT_LOSS 4194304
#define OUT_IDX  4194305
#define OUT_NCB  4210689
#define OUT_NCS  5259265
#define OUT_NES  5263361

typedef unsigned short u16;
typedef unsigned long long u64;
typedef short short8 __attribute__((ext_vector_type(8)));
typedef float f32x4 __attribute__((ext_vector_type(4)));

// ---------------------------------------------------------------------------
// numpy-faithful pairwise sum of squares (validated round 9 — do not touch).
// ---------------------------------------------------------------------------
__device__ __forceinline__ float np_sumsq_row(const float* __restrict__ p) {
    float halves[2];
#pragma unroll
    for (int h = 0; h < 2; ++h) {
        const float* q = p + h * 128;
        float r[8];
        {
            float4 v0 = *(const float4*)(q);
            float4 v1 = *(const float4*)(q + 4);
            r[0] = __fmul_rn(v0.x, v0.x); r[1] = __fmul_rn(v0.y, v0.y);
            r[2] = __fmul_rn(v0.z, v0.z); r[3] = __fmul_rn(v0.w, v0.w);
            r[4] = __fmul_rn(v1.x, v1.x); r[5] = __fmul_rn(v1.y, v1.y);
            r[6] = __fmul_rn(v1.z, v1.z); r[7] = __fmul_rn(v1.w, v1.w);
        }
#pragma unroll
        for (int t = 1; t < 16; ++t) {
            float4 v0 = *(const float4*)(q + 8 * t);
            float4 v1 = *(const float4*)(q + 8 * t + 4);
            r[0] = __fadd_rn(r[0], __fmul_rn(v0.x, v0.x));
            r[1] = __fadd_rn(r[1], __fmul_rn(v0.y, v0.y));
            r[2] = __fadd_rn(r[2], __fmul_rn(v0.z, v0.z));
            r[3] = __fadd_rn(r[3], __fmul_rn(v0.w, v0.w));
            r[4] = __fadd_rn(r[4], __fmul_rn(v1.x, v1.x));
            r[5] = __fadd_rn(r[5], __fmul_rn(v1.y, v1.y));
            r[6] = __fadd_rn(r[6], __fmul_rn(v1.z, v1.z));
            r[7] = __fadd_rn(r[7], __fmul_rn(v1.w, v1.w));
        }
        const float s01 = __fadd_rn(r[0], r[1]);
        const float s23 = __fadd_rn(r[2], r[3]);
        const float s45 = __fadd_rn(r[4], r[5]);
        const float s67 = __fadd_rn(r[6], r[7]);
        halves[h] = __fadd_rn(__fadd_rn(s01, s23), __fadd_rn(s45, s67));
    }
    return __fadd_rn(halves[0], halves[1]);
}

__global__ void cnorm_kernel(const float* __restrict__ cb, float* __restrict__ cnorm) {
    const int row = blockIdx.x * 256 + threadIdx.x;
    if (row < K_CODES) cnorm[row] = np_sumsq_row(&cb[(size_t)row * DIM]);
}

__global__ void znorm_kernel(const float* __restrict__ z, float* __restrict__ znorm) {
    const int row = blockIdx.x * 256 + threadIdx.x;
    if (row < B_ROWS) znorm[row] = np_sumsq_row(&z[(size_t)row * DIM]);
}

// ---------------------------------------------------------------------------
// helpers for the MFMA scorer
// ---------------------------------------------------------------------------
__device__ __forceinline__ u16 f32_to_bf16_rne(float f) {
    unsigned u = __float_as_uint(f);
    unsigned rounding = 0x7FFFu + ((u >> 16) & 1u);
    return (u16)((u + rounding) >> 16);
}
__device__ __forceinline__ unsigned mono_encode(float f) {
    unsigned u = __float_as_uint(f);
    return (u & 0x80000000u) ? ~u : (u | 0x80000000u);
}
__device__ __forceinline__ float mono_decode(unsigned m) {
    unsigned u = (m & 0x80000000u) ? (m ^ 0x80000000u) : ~m;
    return __uint_as_float(u);
}
__device__ __forceinline__ u64 umin64(u64 a, u64 b) { return a < b ? a : b; }
__device__ __forceinline__ u64 umax64(u64 a, u64 b) { return a < b ? b : a; }

// ---------------------------------------------------------------------------
// MFMA bf16 scoring + per-row top-4 per 1024-code split.
// s~ = cnorm[c] - 2*dot(bf16(z_row), bf16(cb_c)).  Keys packed (mono(val)<<32)|code
// so u64 min == (val, lowest index) lexicographic — matches np.argmin ties.
// A/B frags use IDENTICAL lane->(idx,k) mapping so any k-permutation cancels.
// C/D layout: col=lane&15 (codes), row=(lane>>4)*4+reg  [m89-verified].
// ---------------------------------------------------------------------------
#define SC_LDA 40            // ushorts per LDS row: 32 + 8 pad (80 B, 16B-aligned)
#define EPS_MARGIN 3.5e-4f

__global__ __launch_bounds__(256) void score_kernel(
    const float* __restrict__ z, const float* __restrict__ cb,
    const float* __restrict__ cnorm, u64* __restrict__ t4)
{
    __shared__ __align__(16) u16 Alds[128 * SC_LDA];
    __shared__ __align__(16) u16 Blds[128 * SC_LDA];
    const int tid     = threadIdx.x;
    const int split   = blockIdx.x & 3;
    const int rowTile = blockIdx.x >> 2;
    const int row0    = rowTile * 128;
    const int code0   = split * 1024;
    const int wid  = tid >> 6;
    const int lane = tid & 63;
    const int l15  = lane & 15;
    const int kg   = lane >> 4;
    const int srow = tid >> 1;   // staging row 0..127
    const int sh   = tid & 1;    // staging half (16 elems each)

    u64 p0[8], p1[8];            // per-lane sorted top-2 per row-slot
#pragma unroll
    for (int i = 0; i < 8; ++i) { p0[i] = ~0ULL; p1[i] = ~0ULL; }

    for (int ct = 0; ct < 8; ++ct) {           // 8 x 128-code tiles per split
        f32x4 acc[2][8];
#pragma unroll
        for (int a = 0; a < 2; ++a)
#pragma unroll
            for (int b = 0; b < 8; ++b) acc[a][b] = (f32x4){0.f, 0.f, 0.f, 0.f};

        for (int kt = 0; kt < 8; ++kt) {       // K = 256 in steps of 32
            __syncthreads();
            {   // stage A: 16 f32 -> bf16
                const float* src = &z[(size_t)(row0 + srow) * DIM + kt * 32 + sh * 16];
                int w[8];
#pragma unroll
                for (int q = 0; q < 4; ++q) {
                    float4 v = *(const float4*)(src + q * 4);
                    u16 a0 = f32_to_bf16_rne(v.x), a1 = f32_to_bf16_rne(v.y);
                    u16 a2 = f32_to_bf16_rne(v.z), a3 = f32_to_bf16_rne(v.w);
                    w[q * 2]     = (int)a0 | ((int)a1 << 16);
                    w[q * 2 + 1] = (int)a2 | ((int)a3 << 16);
                }
                int4* dst = (int4*)&Alds[srow * SC_LDA + sh * 16];
                dst[0] = make_int4(w[0], w[1], w[2], w[3]);
                dst[1] = make_int4(w[4], w[5], w[6], w[7]);
            }
            {   // stage B: codes
                const float* src = &cb[(size_t)(code0 + ct * 128 + srow) * DIM + kt * 32 + sh * 16];
                int w[8];
#pragma unroll
                for (int q = 0; q < 4; ++q) {
                    float4 v = *(const float4*)(src + q * 4);
                    u16 a0 = f32_to_bf16_rne(v.x), a1 = f32_to_bf16_rne(v.y);
                    u16 a2 = f32_to_bf16_rne(v.z), a3 = f32_to_bf16_rne(v.w);
                    w[q * 2]     = (int)a0 | ((int)a1 << 16);
                    w[q * 2 + 1] = (int)a2 | ((int)a3 << 16);
                }
                int4* dst = (int4*)&Blds[srow * SC_LDA + sh * 16];
                dst[0] = make_int4(w[0], w[1], w[2], w[3]);
                dst[1] = make_int4(w[4], w[5], w[6], w[7]);
            }
            __syncthreads();
            // fragments: lane -> (idx = l15, k = kg*8 + j) for BOTH A and B
            short8 af0 = *(const short8*)&Alds[(wid * 32 +  0 + l15) * SC_LDA + kg * 8];
            short8 af1 = *(const short8*)&Alds[(wid * 32 + 16 + l15) * SC_LDA + kg * 8];
#pragma unroll
            for (int fj = 0; fj < 8; ++fj) {
                short8 bf = *(const short8*)&Blds[(fj * 16 + l15) * SC_LDA + kg * 8];
                acc[0][fj] = __builtin_amdgcn_mfma_f32_16x16x32_bf16(af0, bf, acc[0][fj], 0, 0, 0);
                acc[1][fj] = __builtin_amdgcn_mfma_f32_16x16x32_bf16(af1, bf, acc[1][fj], 0, 0, 0);
            }
        }
        // epilogue: s~ and top-2 insert (codes per lane: col = l15)
#pragma unroll
        for (int fj = 0; fj < 8; ++fj) {
            const int code = code0 + ct * 128 + fj * 16 + l15;
            const float cn = cnorm[code];
#pragma unroll
            for (int fi = 0; fi < 2; ++fi) {
#pragma unroll
                for (int reg = 0; reg < 4; ++reg) {
                    const float sv = cn - 2.0f * acc[fi][fj][reg];
                    const u64 key = ((u64)mono_encode(sv) << 32) | (unsigned)code;
                    const int rs = fi * 4 + reg;
                    if (key < p1[rs]) {
                        if (key < p0[rs]) { p1[rs] = p0[rs]; p0[rs] = key; }
                        else p1[rs] = key;
                    }
                }
            }
        }
    }
    // cross-lane (16-lane group, same kg => same rows) bitonic merge to top-4
#pragma unroll
    for (int rs = 0; rs < 8; ++rs) {
        u64 s0 = p0[rs], s1 = p1[rs], s2 = ~0ULL, s3 = ~0ULL;
#pragma unroll
        for (int m = 1; m < 16; m <<= 1) {
            u64 b0 = __shfl_xor(s0, m), b1 = __shfl_xor(s1, m);
            u64 b2 = __shfl_xor(s2, m), b3 = __shfl_xor(s3, m);
            u64 t0 = umin64(s0, b3), t1 = umin64(s1, b2);
            u64 t2 = umin64(s2, b1), t3 = umin64(s3, b0);
            u64 u0 = umin64(t0, t2), u2 = umax64(t0, t2);
            u64 u1 = umin64(t1, t3), u3 = umax64(t1, t3);
            s0 = umin64(u0, u1); s1 = umax64(u0, u1);
            s2 = umin64(u2, u3); s3 = umax64(u2, u3);
        }
        if (l15 == 0) {
            const int row = row0 + wid * 32 + (rs >> 2) * 16 + kg * 4 + (rs & 3);
            t4[(size_t)(split * 4 + 0) * B_ROWS + row] = s0;
            t4[(size_t)(split * 4 + 1) * B_ROWS + row] = s1;
            t4[(size_t)(split * 4 + 2) * B_ROWS + row] = s2;
            t4[(size_t)(split * 4 + 3) * B_ROWS + row] = s3;
        }
    }
}

// ---------------------------------------------------------------------------
// candidate merge + EXACT rescore (round-9-validated f32 chain, k in order)
// ---------------------------------------------------------------------------
__global__ void rescore_kernel(const float* __restrict__ z, const float* __restrict__ cb,
                               const float* __restrict__ cnorm, const float* __restrict__ znorm,
                               const u64* __restrict__ t4, int* __restrict__ indices)
{
    const int row = blockIdx.x * 256 + threadIdx.x;
    u64 kmin = ~0ULL;
    for (int i = 0; i < 16; ++i) {
        const u64 k = t4[(size_t)i * B_ROWS + row];
        if (k < kmin) kmin = k;
    }
    const float thr = mono_decode((unsigned)(kmin >> 32)) + EPS_MARGIN;
    const float zn = znorm[row];
    const float* zp = &z[(size_t)row * DIM];
    float bs = 0.f; int bi = -1;
    for (int i = 0; i < 16; ++i) {
        const u64 k = t4[(size_t)i * B_ROWS + row];
        const float v = mono_decode((unsigned)(k >> 32));
        const int code = (int)(k & 0xFFFFFFFFu);
        if (v <= thr) {   // sentinel decodes to NaN -> excluded
            const float* cp = &cb[(size_t)code * DIM];
            float acc = 0.f;
#pragma unroll 8
            for (int kk = 0; kk < DIM; ++kk) acc = fmaf(zp[kk], cp[kk], acc);
            const float t = __fsub_rn(zn, __fmul_rn(2.0f, acc));
            const float s = __fadd_rn(t, cnorm[code]);
            if (bi < 0 || s < bs || (s == bs && code < bi)) { bs = s; bi = code; }
        }
    }
    indices[row] = bi;
}

// ---------------- downstream (unchanged, round-9-validated) ----------------
__global__ void count_kernel(const int* __restrict__ idx, int* __restrict__ counts) {
    const int b = blockIdx.x * 256 + threadIdx.x;
    atomicAdd(&counts[idx[b]], 1);
}

__global__ void scan_kernel(const int* __restrict__ counts, int* __restrict__ offsets,
                            int* __restrict__ cursor) {
    const int lane = threadIdx.x;   // 64 lanes
    const int base = lane * 64;
    int s = 0;
    for (int i = 0; i < 64; ++i) s += counts[base + i];
    int v = s;
#pragma unroll
    for (int d = 1; d < 64; d <<= 1) {
        const int o = __shfl_up(v, d);
        if (lane >= d) v += o;
    }
    int run = v - s;
    for (int i = 0; i < 64; ++i) {
        const int c = counts[base + i];
        offsets[base + i] = run;
        cursor[base + i]  = run;
        run += c;
    }
}

__global__ void scatter_kernel(const int* __restrict__ idx, int* __restrict__ cursor,
                               int* __restrict__ buckets) {
    const int b = blockIdx.x * 256 + threadIdx.x;
    const int pos = atomicAdd(&cursor[idx[b]], 1);
    buckets[pos] = b;
}

__global__ void update_kernel(const float* __restrict__ z,
                              const float* __restrict__ ema_es, const float* __restrict__ ema_cs,
                              const int* __restrict__ counts, const int* __restrict__ offsets,
                              const int* __restrict__ buckets,
                              float* __restrict__ out_nes, float* __restrict__ out_ncs,
                              float* __restrict__ ws_ncs) {
    const int k = blockIdx.x;
    const int d = threadIdx.x;
    const int c = counts[k];
    const int o = offsets[k];
    float acc = 0.f;
    for (int j = 0; j < c; ++j) {
        const int r = buckets[o + j];
        acc += z[(size_t)r * DIM + d];
    }
    out_nes[(size_t)k * DIM + d] = 0.99f * ema_es[(size_t)k * DIM + d] + 0.01f * acc;
    if (d == 0) {
        const float ncs = 0.99f * ema_cs[k] + 0.01f * (float)c;
        out_ncs[k] = ncs;
        ws_ncs[k]  = ncs;
    }
}

__global__ void nsum_kernel(const float* __restrict__ ws_ncs, float* __restrict__ ws_n) {
    __shared__ float red[256];
    const int tid = threadIdx.x;
    float s = 0.f;
    for (int i = tid; i < K_CODES; i += 256) s += ws_ncs[i];
    red[tid] = s; __syncthreads();
    for (int st = 128; st > 0; st >>= 1) {
        if (tid < st) red[tid] += red[tid + st];
        __syncthreads();
    }
    if (tid == 0) ws_n[0] = red[0];
}

__global__ void codebook_kernel(const float* __restrict__ out_nes, const float* __restrict__ ws_ncs,
                                const float* __restrict__ ws_n, float* __restrict__ out_ncb) {
    const int k = blockIdx.x;
    const int d = threadIdx.x;
    const float n = ws_n[0];
    const float cs = (ws_ncs[k] + 1e-5f) / (n + (float)K_CODES * 1e-5f) * n;
    out_ncb[(size_t)k * DIM + d] = out_nes[(size_t)k * DIM + d] / cs;
}

__global__ void gather_loss_kernel(const float* __restrict__ z, const float* __restrict__ cb,
                                   const int* __restrict__ idx,
                                   float* __restrict__ out_zq, float* __restrict__ out_loss) {
    __shared__ float red[256];
    const int tid = threadIdx.x;
    float acc = 0.f;
    for (size_t i = blockIdx.x * 256 + tid; i < (size_t)B_ROWS * DIM; i += (size_t)gridDim.x * 256) {
        const int b = (int)(i >> 8);
        const int d = (int)(i & 255);
        const int k = idx[b];
        const float zq = cb[(size_t)k * DIM + d];
        const float ze = z[i];
        out_zq[i] = __fadd_rn(ze, __fsub_rn(zq, ze));
        const float diff = zq - ze;
        acc += diff * diff;
    }
    red[tid] = acc; __syncthreads();
    for (int st = 128; st > 0; st >>= 1) {
        if (tid < st) red[tid] += red[tid + st];
        __syncthreads();
    }
    if (tid == 0) atomicAdd(out_loss, red[0] * (0.25f / 4194304.0f));
}

__global__ void idx_out_kernel(const int* __restrict__ idx, float* __restrict__ out) {
    const int b = blockIdx.x * 256 + threadIdx.x;
    out[b] = (float)idx[b];
}

extern "C" void kernel_launch(void* const* d_in, const int* in_sizes, int n_in,
                              void* d_out, int out_size, void* d_ws, size_t ws_size,
                              hipStream_t stream) {
    const float* z      = (const float*)d_in[0];
    const float* cb     = (const float*)d_in[1];
    const float* ema_cs = (const float*)d_in[2];
    const float* ema_es = (const float*)d_in[3];
    float* out = (float*)d_out;

    char* p = (char*)d_ws;
    int*   indices = (int*)p;   p += B_ROWS * 4;
    int*   counts  = (int*)p;   p += K_CODES * 4;
    int*   offsets = (int*)p;   p += K_CODES * 4;
    int*   cursor  = (int*)p;   p += K_CODES * 4;
    int*   buckets = (int*)p;   p += B_ROWS * 4;
    float* cnorm   = (float*)p; p += K_CODES * 4;
    float* znorm   = (float*)p; p += B_ROWS * 4;
    float* ws_ncs  = (float*)p; p += K_CODES * 4;
    float* ws_n    = (float*)p; p += 256;
    u64*   t4      = (u64*)p;   p += (size_t)16 * B_ROWS * 8;   // 2 MB

    hipMemsetAsync(counts, 0, K_CODES * 4, stream);
    hipMemsetAsync(out + OUT_LOSS, 0, 4, stream);

    cnorm_kernel<<<(K_CODES + 255) / 256, 256, 0, stream>>>(cb, cnorm);
    znorm_kernel<<<(B_ROWS + 255) / 256, 256, 0, stream>>>(z, znorm);
    score_kernel<<<(B_ROWS / 128) * 4, 256, 0, stream>>>(z, cb, cnorm, t4);
    rescore_kernel<<<B_ROWS / 256, 256, 0, stream>>>(z, cb, cnorm, znorm, t4, indices);
    count_kernel<<<B_ROWS / 256, 256, 0, stream>>>(indices, counts);
    scan_kernel<<<1, 64, 0, stream>>>(counts, offsets, cursor);
    scatter_kernel<<<B_ROWS / 256, 256, 0, stream>>>(indices, cursor, buckets);
    update_kernel<<<K_CODES, 256, 0, stream>>>(z, ema_es, ema_cs, counts, offsets, buckets,
                                               out + OUT_NES, out + OUT_NCS, ws_ncs);
    nsum_kernel<<<1, 256, 0, stream>>>(ws_ncs, ws_n);
    codebook_kernel<<<K_CODES, 256, 0, stream>>>(out + OUT_NES, ws_ncs, ws_n, out + OUT_NCB);
    gather_loss_kernel<<<1024, 256, 0, stream>>>(z, cb, indices, out + OUT_ZQ, out + OUT_LOSS);
    idx_out_kernel<<<B_ROWS / 256, 256, 0, stream>>>(indices, out + OUT_IDX);
}

// Round 11
// 415.486 us; speedup vs baseline: 1.3671x; 1.0873x over previous
//
#include <hip/hip_runtime.h>
#include <math.h>

#define B_ROWS 16384
#define DIM    256
#define K_CODES 4096

// d_out element offsets (f32), reference return order:
// z_q_st (16384x256), vq_loss (1), indices (16384),
// new_codebook (4096x256), new_cluster_size (4096), new_embed_sum (4096x256)
#define OUT_ZQ   0
#define OUT_LOSS 4194304
#define OUT_IDX  4194305
#define OUT_NCB  4210689
#define OUT_NCS  5259265
#define OUT_NES  5263361

typedef unsigned short u16;
typedef unsigned long long u64;
typedef short short8 __attribute__((ext_vector_type(8)));
typedef float f32x4 __attribute__((ext_vector_type(4)));

__device__ __forceinline__ u16 f32_to_bf16_rne(float f) {
    unsigned u = __float_as_uint(f);
    unsigned rounding = 0x7FFFu + ((u >> 16) & 1u);
    return (u16)((u + rounding) >> 16);
}
__device__ __forceinline__ int4 pack8(float4 v0, float4 v1) {
    return make_int4(
        (int)f32_to_bf16_rne(v0.x) | ((int)f32_to_bf16_rne(v0.y) << 16),
        (int)f32_to_bf16_rne(v0.z) | ((int)f32_to_bf16_rne(v0.w) << 16),
        (int)f32_to_bf16_rne(v1.x) | ((int)f32_to_bf16_rne(v1.y) << 16),
        (int)f32_to_bf16_rne(v1.z) | ((int)f32_to_bf16_rne(v1.w) << 16));
}
__device__ __forceinline__ unsigned mono_encode(float f) {
    unsigned u = __float_as_uint(f);
    return (u & 0x80000000u) ? ~u : (u | 0x80000000u);
}
__device__ __forceinline__ float mono_decode(unsigned m) {
    unsigned u = (m & 0x80000000u) ? (m ^ 0x80000000u) : ~m;
    return __uint_as_float(u);
}
__device__ __forceinline__ u64 umin64(u64 a, u64 b) { return a < b ? a : b; }
__device__ __forceinline__ u64 umax64(u64 a, u64 b) { return a < b ? b : a; }

// ---------------------------------------------------------------------------
// numpy-faithful pairwise sum of squares (validated r9 rounding chain) FUSED
// with f32->bf16 RNE conversion of the row (identical bits to r10's in-kernel
// conversion). Summation tree untouched: squares of ORIGINAL f32 values.
// ---------------------------------------------------------------------------
__device__ __forceinline__ float np_convsumsq_row(const float* __restrict__ p,
                                                  u16* __restrict__ dst) {
    float halves[2];
#pragma unroll
    for (int h = 0; h < 2; ++h) {
        const float* q = p + h * 128;
        int4* d = (int4*)(dst + h * 128);
        float r[8];
        {
            float4 v0 = *(const float4*)(q);
            float4 v1 = *(const float4*)(q + 4);
            d[0] = pack8(v0, v1);
            r[0] = __fmul_rn(v0.x, v0.x); r[1] = __fmul_rn(v0.y, v0.y);
            r[2] = __fmul_rn(v0.z, v0.z); r[3] = __fmul_rn(v0.w, v0.w);
            r[4] = __fmul_rn(v1.x, v1.x); r[5] = __fmul_rn(v1.y, v1.y);
            r[6] = __fmul_rn(v1.z, v1.z); r[7] = __fmul_rn(v1.w, v1.w);
        }
#pragma unroll
        for (int t = 1; t < 16; ++t) {
            float4 v0 = *(const float4*)(q + 8 * t);
            float4 v1 = *(const float4*)(q + 8 * t + 4);
            d[t] = pack8(v0, v1);
            r[0] = __fadd_rn(r[0], __fmul_rn(v0.x, v0.x));
            r[1] = __fadd_rn(r[1], __fmul_rn(v0.y, v0.y));
            r[2] = __fadd_rn(r[2], __fmul_rn(v0.z, v0.z));
            r[3] = __fadd_rn(r[3], __fmul_rn(v0.w, v0.w));
            r[4] = __fadd_rn(r[4], __fmul_rn(v1.x, v1.x));
            r[5] = __fadd_rn(r[5], __fmul_rn(v1.y, v1.y));
            r[6] = __fadd_rn(r[6], __fmul_rn(v1.z, v1.z));
            r[7] = __fadd_rn(r[7], __fmul_rn(v1.w, v1.w));
        }
        const float s01 = __fadd_rn(r[0], r[1]);
        const float s23 = __fadd_rn(r[2], r[3]);
        const float s45 = __fadd_rn(r[4], r[5]);
        const float s67 = __fadd_rn(r[6], r[7]);
        halves[h] = __fadd_rn(__fadd_rn(s01, s23), __fadd_rn(s45, s67));
    }
    return __fadd_rn(halves[0], halves[1]);
}

__global__ void zconv_kernel(const float* __restrict__ z, u16* __restrict__ zbf,
                             float* __restrict__ znorm) {
    const int row = blockIdx.x * 256 + threadIdx.x;
    if (row < B_ROWS)
        znorm[row] = np_convsumsq_row(&z[(size_t)row * DIM], &zbf[(size_t)row * DIM]);
}

__global__ void cconv_kernel(const float* __restrict__ cb, u16* __restrict__ cbbf,
                             float* __restrict__ cnorm) {
    const int row = blockIdx.x * 256 + threadIdx.x;
    if (row < K_CODES)
        cnorm[row] = np_convsumsq_row(&cb[(size_t)row * DIM], &cbbf[(size_t)row * DIM]);
}

// ---------------------------------------------------------------------------
// MFMA bf16 scoring + per-row top-4 per 1024-code split (r10-validated logic).
// Changes vs r10: A fragments held in registers (loaded once from zbf);
// B staged from pre-converted cbbf as a pure 32B copy (no ALU conversion).
// A/B frags use IDENTICAL lane->(idx,k) mapping so any k-permutation cancels.
// C/D layout: col=lane&15 (codes), row=(lane>>4)*4+reg  [m89-verified].
// ---------------------------------------------------------------------------
#define SC_LDA 40            // ushorts per LDS row: 32 + 8 pad (80 B) => ~2-way
#define EPS_MARGIN 3.5e-4f

__global__ __launch_bounds__(256) void score_kernel(
    const u16* __restrict__ zbf, const u16* __restrict__ cbbf,
    const float* __restrict__ cnorm, u64* __restrict__ t4)
{
    __shared__ __align__(16) u16 Blds[128 * SC_LDA];
    const int tid     = threadIdx.x;
    const int split   = blockIdx.x & 3;
    const int rowTile = blockIdx.x >> 2;
    const int row0    = rowTile * 128;
    const int code0   = split * 1024;
    const int wid  = tid >> 6;
    const int lane = tid & 63;
    const int l15  = lane & 15;
    const int kg   = lane >> 4;
    const int srow = tid >> 1;   // staging row 0..127
    const int sh   = tid & 1;    // staging half (16 ushorts = 32B each)

    // A fragments in registers: rows wid*32 + fi*16 + l15, all 8 k-tiles
    short8 af[2][8];
#pragma unroll
    for (int fi = 0; fi < 2; ++fi) {
        const u16* ap = &zbf[(size_t)(row0 + wid * 32 + fi * 16 + l15) * DIM];
#pragma unroll
        for (int kt = 0; kt < 8; ++kt)
            af[fi][kt] = *(const short8*)&ap[kt * 32 + kg * 8];
    }

    u64 p0[8], p1[8];            // per-lane sorted top-2 per row-slot
#pragma unroll
    for (int i = 0; i < 8; ++i) { p0[i] = ~0ULL; p1[i] = ~0ULL; }

    for (int ct = 0; ct < 8; ++ct) {           // 8 x 128-code tiles per split
        f32x4 acc[2][8];
#pragma unroll
        for (int a = 0; a < 2; ++a)
#pragma unroll
            for (int b = 0; b < 8; ++b) acc[a][b] = (f32x4){0.f, 0.f, 0.f, 0.f};

        for (int kt = 0; kt < 8; ++kt) {       // K = 256 in steps of 32
            __syncthreads();
            {   // stage B: pure 32B copy from pre-converted cbbf
                const u16* src = &cbbf[(size_t)(code0 + ct * 128 + srow) * DIM + kt * 32 + sh * 16];
                int4 w0 = *(const int4*)(src);
                int4 w1 = *(const int4*)(src + 8);
                int4* dst = (int4*)&Blds[srow * SC_LDA + sh * 16];
                dst[0] = w0; dst[1] = w1;
            }
            __syncthreads();
#pragma unroll
            for (int fj = 0; fj < 8; ++fj) {
                short8 bf = *(const short8*)&Blds[(fj * 16 + l15) * SC_LDA + kg * 8];
                acc[0][fj] = __builtin_amdgcn_mfma_f32_16x16x32_bf16(af[0][kt], bf, acc[0][fj], 0, 0, 0);
                acc[1][fj] = __builtin_amdgcn_mfma_f32_16x16x32_bf16(af[1][kt], bf, acc[1][fj], 0, 0, 0);
            }
        }
        // epilogue: s~ = cnorm - 2*dot; top-2 insert per row-slot
#pragma unroll
        for (int fj = 0; fj < 8; ++fj) {
            const int code = code0 + ct * 128 + fj * 16 + l15;
            const float cn = cnorm[code];
#pragma unroll
            for (int fi = 0; fi < 2; ++fi) {
#pragma unroll
                for (int reg = 0; reg < 4; ++reg) {
                    const float sv = cn - 2.0f * acc[fi][fj][reg];
                    const u64 key = ((u64)mono_encode(sv) << 32) | (unsigned)code;
                    const int rs = fi * 4 + reg;
                    if (key < p1[rs]) {
                        if (key < p0[rs]) { p1[rs] = p0[rs]; p0[rs] = key; }
                        else p1[rs] = key;
                    }
                }
            }
        }
    }
    // cross-lane (16-lane group, same kg => same rows) bitonic merge to top-4
#pragma unroll
    for (int rs = 0; rs < 8; ++rs) {
        u64 s0 = p0[rs], s1 = p1[rs], s2 = ~0ULL, s3 = ~0ULL;
#pragma unroll
        for (int m = 1; m < 16; m <<= 1) {
            u64 b0 = __shfl_xor(s0, m), b1 = __shfl_xor(s1, m);
            u64 b2 = __shfl_xor(s2, m), b3 = __shfl_xor(s3, m);
            u64 t0 = umin64(s0, b3), t1 = umin64(s1, b2);
            u64 t2 = umin64(s2, b1), t3 = umin64(s3, b0);
            u64 u0 = umin64(t0, t2), u2 = umax64(t0, t2);
            u64 u1 = umin64(t1, t3), u3 = umax64(t1, t3);
            s0 = umin64(u0, u1); s1 = umax64(u0, u1);
            s2 = umin64(u2, u3); s3 = umax64(u2, u3);
        }
        if (l15 == 0) {
            const int row = row0 + wid * 32 + (rs >> 2) * 16 + kg * 4 + (rs & 3);
            t4[(size_t)(split * 4 + 0) * B_ROWS + row] = s0;
            t4[(size_t)(split * 4 + 1) * B_ROWS + row] = s1;
            t4[(size_t)(split * 4 + 2) * B_ROWS + row] = s2;
            t4[(size_t)(split * 4 + 3) * B_ROWS + row] = s3;
        }
    }
}

// ---------------------------------------------------------------------------
// candidate merge + EXACT rescore (r9-validated f32 chain) + fused
// count histogram + float index output.
// ---------------------------------------------------------------------------
__global__ void rescore_kernel(const float* __restrict__ z, const float* __restrict__ cb,
                               const float* __restrict__ cnorm, const float* __restrict__ znorm,
                               const u64* __restrict__ t4, int* __restrict__ indices,
                               int* __restrict__ counts, float* __restrict__ out_idx)
{
    const int row = blockIdx.x * 256 + threadIdx.x;
    u64 kmin = ~0ULL;
    for (int i = 0; i < 16; ++i) {
        const u64 k = t4[(size_t)i * B_ROWS + row];
        if (k < kmin) kmin = k;
    }
    const float thr = mono_decode((unsigned)(kmin >> 32)) + EPS_MARGIN;
    const float zn = znorm[row];
    const float* zp = &z[(size_t)row * DIM];
    float bs = 0.f; int bi = -1;
    for (int i = 0; i < 16; ++i) {
        const u64 k = t4[(size_t)i * B_ROWS + row];
        const float v = mono_decode((unsigned)(k >> 32));
        const int code = (int)(k & 0xFFFFFFFFu);
        if (v <= thr) {   // sentinel decodes to NaN -> excluded
            const float* cp = &cb[(size_t)code * DIM];
            float acc = 0.f;
#pragma unroll 8
            for (int kk = 0; kk < DIM; ++kk) acc = fmaf(zp[kk], cp[kk], acc);
            const float t = __fsub_rn(zn, __fmul_rn(2.0f, acc));
            const float s = __fadd_rn(t, cnorm[code]);
            if (bi < 0 || s < bs || (s == bs && code < bi)) { bs = s; bi = code; }
        }
    }
    indices[row] = bi;
    out_idx[row] = (float)bi;
    atomicAdd(&counts[bi], 1);
}

// ---------------- downstream (unchanged, r9-validated) ----------------
__global__ void scan_kernel(const int* __restrict__ counts, int* __restrict__ offsets,
                            int* __restrict__ cursor) {
    const int lane = threadIdx.x;   // 64 lanes
    const int base = lane * 64;
    int s = 0;
    for (int i = 0; i < 64; ++i) s += counts[base + i];
    int v = s;
#pragma unroll
    for (int d = 1; d < 64; d <<= 1) {
        const int o = __shfl_up(v, d);
        if (lane >= d) v += o;
    }
    int run = v - s;
    for (int i = 0; i < 64; ++i) {
        const int c = counts[base + i];
        offsets[base + i] = run;
        cursor[base + i]  = run;
        run += c;
    }
}

__global__ void scatter_kernel(const int* __restrict__ idx, int* __restrict__ cursor,
                               int* __restrict__ buckets) {
    const int b = blockIdx.x * 256 + threadIdx.x;
    const int pos = atomicAdd(&cursor[idx[b]], 1);
    buckets[pos] = b;
}

__global__ void update_kernel(const float* __restrict__ z,
                              const float* __restrict__ ema_es, const float* __restrict__ ema_cs,
                              const int* __restrict__ counts, const int* __restrict__ offsets,
                              const int* __restrict__ buckets,
                              float* __restrict__ out_nes, float* __restrict__ out_ncs,
                              float* __restrict__ ws_ncs) {
    const int k = blockIdx.x;
    const int d = threadIdx.x;
    const int c = counts[k];
    const int o = offsets[k];
    float acc = 0.f;
    for (int j = 0; j < c; ++j) {
        const int r = buckets[o + j];
        acc += z[(size_t)r * DIM + d];
    }
    out_nes[(size_t)k * DIM + d] = 0.99f * ema_es[(size_t)k * DIM + d] + 0.01f * acc;
    if (d == 0) {
        const float ncs = 0.99f * ema_cs[k] + 0.01f * (float)c;
        out_ncs[k] = ncs;
        ws_ncs[k]  = ncs;
    }
}

__global__ void nsum_kernel(const float* __restrict__ ws_ncs, float* __restrict__ ws_n) {
    __shared__ float red[256];
    const int tid = threadIdx.x;
    float s = 0.f;
    for (int i = tid; i < K_CODES; i += 256) s += ws_ncs[i];
    red[tid] = s; __syncthreads();
    for (int st = 128; st > 0; st >>= 1) {
        if (tid < st) red[tid] += red[tid + st];
        __syncthreads();
    }
    if (tid == 0) ws_n[0] = red[0];
}

__global__ void codebook_kernel(const float* __restrict__ out_nes, const float* __restrict__ ws_ncs,
                                const float* __restrict__ ws_n, float* __restrict__ out_ncb) {
    const int k = blockIdx.x;
    const int d = threadIdx.x;
    const float n = ws_n[0];
    const float cs = (ws_ncs[k] + 1e-5f) / (n + (float)K_CODES * 1e-5f) * n;
    out_ncb[(size_t)k * DIM + d] = out_nes[(size_t)k * DIM + d] / cs;
}

__global__ void gather_loss_kernel(const float* __restrict__ z, const float* __restrict__ cb,
                                   const int* __restrict__ idx,
                                   float* __restrict__ out_zq, float* __restrict__ out_loss) {
    __shared__ float red[256];
    const int tid = threadIdx.x;
    float acc = 0.f;
    for (size_t i = blockIdx.x * 256 + tid; i < (size_t)B_ROWS * DIM; i += (size_t)gridDim.x * 256) {
        const int b = (int)(i >> 8);
        const int d = (int)(i & 255);
        const int k = idx[b];
        const float zq = cb[(size_t)k * DIM + d];
        const float ze = z[i];
        out_zq[i] = __fadd_rn(ze, __fsub_rn(zq, ze));
        const float diff = zq - ze;
        acc += diff * diff;
    }
    red[tid] = acc; __syncthreads();
    for (int st = 128; st > 0; st >>= 1) {
        if (tid < st) red[tid] += red[tid + st];
        __syncthreads();
    }
    if (tid == 0) atomicAdd(out_loss, red[0] * (0.25f / 4194304.0f));
}

extern "C" void kernel_launch(void* const* d_in, const int* in_sizes, int n_in,
                              void* d_out, int out_size, void* d_ws, size_t ws_size,
                              hipStream_t stream) {
    const float* z      = (const float*)d_in[0];
    const float* cb     = (const float*)d_in[1];
    const float* ema_cs = (const float*)d_in[2];
    const float* ema_es = (const float*)d_in[3];
    float* out = (float*)d_out;

    char* p = (char*)d_ws;
    u16*   zbf     = (u16*)p;   p += (size_t)B_ROWS * DIM * 2;   // 8 MB
    u16*   cbbf    = (u16*)p;   p += (size_t)K_CODES * DIM * 2;  // 2 MB
    u64*   t4      = (u64*)p;   p += (size_t)16 * B_ROWS * 8;    // 2 MB
    int*   indices = (int*)p;   p += B_ROWS * 4;
    int*   counts  = (int*)p;   p += K_CODES * 4;
    int*   offsets = (int*)p;   p += K_CODES * 4;
    int*   cursor  = (int*)p;   p += K_CODES * 4;
    int*   buckets = (int*)p;   p += B_ROWS * 4;
    float* cnorm   = (float*)p; p += K_CODES * 4;
    float* znorm   = (float*)p; p += B_ROWS * 4;
    float* ws_ncs  = (float*)p; p += K_CODES * 4;
    float* ws_n    = (float*)p; p += 256;

    hipMemsetAsync(counts, 0, K_CODES * 4, stream);
    hipMemsetAsync(out + OUT_LOSS, 0, 4, stream);

    zconv_kernel<<<(B_ROWS + 255) / 256, 256, 0, stream>>>(z, zbf, znorm);
    cconv_kernel<<<(K_CODES + 255) / 256, 256, 0, stream>>>(cb, cbbf, cnorm);
    score_kernel<<<(B_ROWS / 128) * 4, 256, 0, stream>>>(zbf, cbbf, cnorm, t4);
    rescore_kernel<<<B_ROWS / 256, 256, 0, stream>>>(z, cb, cnorm, znorm, t4, indices,
                                                     counts, out + OUT_IDX);
    scan_kernel<<<1, 64, 0, stream>>>(counts, offsets, cursor);
    scatter_kernel<<<B_ROWS / 256, 256, 0, stream>>>(indices, cursor, buckets);
    update_kernel<<<K_CODES, 256, 0, stream>>>(z, ema_es, ema_cs, counts, offsets, buckets,
                                               out + OUT_NES, out + OUT_NCS, ws_ncs);
    nsum_kernel<<<1, 256, 0, stream>>>(ws_ncs, ws_n);
    codebook_kernel<<<K_CODES, 256, 0, stream>>>(out + OUT_NES, ws_ncs, ws_n, out + OUT_NCB);
    gather_loss_kernel<<<1024, 256, 0, stream>>>(z, cb, indices, out + OUT_ZQ, out + OUT_LOSS);
}

// Round 14
// 287.931 us; speedup vs baseline: 1.9727x; 1.4430x over previous
//
#include <hip/hip_runtime.h>
#include <math.h>

#define B_ROWS 16384
#define DIM    256
#define K_CODES 4096

// d_out element offsets (f32), reference return order:
// z_q_st (16384x256), vq_loss (1), indices (16384),
// new_codebook (4096x256), new_cluster_size (4096), new_embed_sum (4096x256)
#define OUT_ZQ   0
#define OUT_LOSS 4194304
#define OUT_IDX  4194305
#define OUT_NCB  4210689
#define OUT_NCS  5259265
#define OUT_NES  5263361

typedef unsigned short u16;
typedef unsigned long long u64;
typedef short short8 __attribute__((ext_vector_type(8)));
typedef float f32x4 __attribute__((ext_vector_type(4)));

__device__ __forceinline__ u16 f32_to_bf16_rne(float f) {
    unsigned u = __float_as_uint(f);
    unsigned rounding = 0x7FFFu + ((u >> 16) & 1u);
    return (u16)((u + rounding) >> 16);
}
__device__ __forceinline__ int4 pack8(float4 v0, float4 v1) {
    return make_int4(
        (int)f32_to_bf16_rne(v0.x) | ((int)f32_to_bf16_rne(v0.y) << 16),
        (int)f32_to_bf16_rne(v0.z) | ((int)f32_to_bf16_rne(v0.w) << 16),
        (int)f32_to_bf16_rne(v1.x) | ((int)f32_to_bf16_rne(v1.y) << 16),
        (int)f32_to_bf16_rne(v1.z) | ((int)f32_to_bf16_rne(v1.w) << 16));
}
__device__ __forceinline__ unsigned mono_encode(float f) {
    unsigned u = __float_as_uint(f);
    return (u & 0x80000000u) ? ~u : (u | 0x80000000u);
}
__device__ __forceinline__ float mono_decode(unsigned m) {
    unsigned u = (m & 0x80000000u) ? (m ^ 0x80000000u) : ~m;
    return __uint_as_float(u);
}
__device__ __forceinline__ u64 umin64(u64 a, u64 b) { return a < b ? a : b; }
__device__ __forceinline__ u64 umax64(u64 a, u64 b) { return a < b ? b : a; }

// ---------------------------------------------------------------------------
// numpy-faithful pairwise sum of squares (validated r9 rounding chain) FUSED
// with f32->bf16 RNE conversion (identical bits to r10/r11). Summation tree
// untouched: squares of ORIGINAL f32 values, np pairwise order.
// ---------------------------------------------------------------------------
__device__ __forceinline__ float np_convsumsq_row(const float* __restrict__ p,
                                                  u16* __restrict__ dst) {
    float halves[2];
#pragma unroll
    for (int h = 0; h < 2; ++h) {
        const float* q = p + h * 128;
        int4* d = (int4*)(dst + h * 128);
        float r[8];
        {
            float4 v0 = *(const float4*)(q);
            float4 v1 = *(const float4*)(q + 4);
            d[0] = pack8(v0, v1);
            r[0] = __fmul_rn(v0.x, v0.x); r[1] = __fmul_rn(v0.y, v0.y);
            r[2] = __fmul_rn(v0.z, v0.z); r[3] = __fmul_rn(v0.w, v0.w);
            r[4] = __fmul_rn(v1.x, v1.x); r[5] = __fmul_rn(v1.y, v1.y);
            r[6] = __fmul_rn(v1.z, v1.z); r[7] = __fmul_rn(v1.w, v1.w);
        }
#pragma unroll
        for (int t = 1; t < 16; ++t) {
            float4 v0 = *(const float4*)(q + 8 * t);
            float4 v1 = *(const float4*)(q + 8 * t + 4);
            d[t] = pack8(v0, v1);
            r[0] = __fadd_rn(r[0], __fmul_rn(v0.x, v0.x));
            r[1] = __fadd_rn(r[1], __fmul_rn(v0.y, v0.y));
            r[2] = __fadd_rn(r[2], __fmul_rn(v0.z, v0.z));
            r[3] = __fadd_rn(r[3], __fmul_rn(v0.w, v0.w));
            r[4] = __fadd_rn(r[4], __fmul_rn(v1.x, v1.x));
            r[5] = __fadd_rn(r[5], __fmul_rn(v1.y, v1.y));
            r[6] = __fadd_rn(r[6], __fmul_rn(v1.z, v1.z));
            r[7] = __fadd_rn(r[7], __fmul_rn(v1.w, v1.w));
        }
        const float s01 = __fadd_rn(r[0], r[1]);
        const float s23 = __fadd_rn(r[2], r[3]);
        const float s45 = __fadd_rn(r[4], r[5]);
        const float s67 = __fadd_rn(r[6], r[7]);
        halves[h] = __fadd_rn(__fadd_rn(s01, s23), __fadd_rn(s45, s67));
    }
    return __fadd_rn(halves[0], halves[1]);
}

__global__ void zconv_kernel(const float* __restrict__ z, u16* __restrict__ zbf,
                             float* __restrict__ znorm) {
    const int row = blockIdx.x * 256 + threadIdx.x;
    if (row < B_ROWS)
        znorm[row] = np_convsumsq_row(&z[(size_t)row * DIM], &zbf[(size_t)row * DIM]);
}

__global__ void cconv_kernel(const float* __restrict__ cb, u16* __restrict__ cbbf,
                             float* __restrict__ cnorm) {
    const int row = blockIdx.x * 256 + threadIdx.x;
    if (row < K_CODES)
        cnorm[row] = np_convsumsq_row(&cb[(size_t)row * DIM], &cbbf[(size_t)row * DIM]);
}

// ---------------------------------------------------------------------------
// MFMA bf16 scoring + per-row top-4 per 1024-code split.
// v3 vs r11: 8 waves/block, each wave owns 16 rows; af[8]/acc[8] fully
// static-indexed (all loops #pragma unroll) so NOTHING spills to scratch
// (rule #20 — r11's af[fi][kt] with runtime kt lived in scratch).
// Arithmetic identical to r11: same bf16 bits, same MFMA shape, same kt
// chain order => bitwise-identical scores and t4 keys.
// A/B frags use IDENTICAL lane->(idx,k) mapping so any k-permutation cancels.
// C/D layout: col=lane&15 (codes), row=(lane>>4)*4+reg  [m89-verified].
// ---------------------------------------------------------------------------
#define SC_LDA 40            // ushorts per LDS row: 32 + 8 pad (80 B)
#define EPS_MARGIN 3.5e-4f

__global__ __launch_bounds__(512) void score_kernel(
    const u16* __restrict__ zbf, const u16* __restrict__ cbbf,
    const float* __restrict__ cnorm, u64* __restrict__ t4)
{
    __shared__ __align__(16) u16 Blds[128 * SC_LDA];
    const int tid   = threadIdx.x;
    const int split = blockIdx.x & 3;
    const int row0  = (blockIdx.x >> 2) * 128;
    const int code0 = split * 1024;
    const int wid  = tid >> 6;       // 0..7 : wave -> 16-row band
    const int lane = tid & 63;
    const int l15  = lane & 15;
    const int kg   = lane >> 4;      // 0..3 : k-group
    const int srow = tid >> 2;       // 0..127 staging row
    const int sq   = tid & 3;        // 16B staging quarter

    // A fragments in registers (static unroll): wave's rows row0+wid*16+l15
    short8 af[8];
    {
        const u16* ap = &zbf[(size_t)(row0 + wid * 16 + l15) * DIM];
#pragma unroll
        for (int kt = 0; kt < 8; ++kt)
            af[kt] = *(const short8*)&ap[kt * 32 + kg * 8];
    }

    u64 p0[4], p1[4];                // per-lane sorted top-2 per row-slot (reg)
#pragma unroll
    for (int i = 0; i < 4; ++i) { p0[i] = ~0ULL; p1[i] = ~0ULL; }

    for (int ct = 0; ct < 8; ++ct) {           // 8 x 128-code tiles per split
        f32x4 acc[8];
#pragma unroll
        for (int j = 0; j < 8; ++j) acc[j] = (f32x4){0.f, 0.f, 0.f, 0.f};

#pragma unroll
        for (int kt = 0; kt < 8; ++kt) {       // K = 256 in steps of 32
            __syncthreads();
            {   // stage B: one 16B copy per thread from pre-converted cbbf
                const u16* src = &cbbf[(size_t)(code0 + ct * 128 + srow) * DIM + kt * 32 + sq * 8];
                *(int4*)&Blds[srow * SC_LDA + sq * 8] = *(const int4*)src;
            }
            __syncthreads();
#pragma unroll
            for (int fj = 0; fj < 8; ++fj) {
                short8 bf = *(const short8*)&Blds[(fj * 16 + l15) * SC_LDA + kg * 8];
                acc[fj] = __builtin_amdgcn_mfma_f32_16x16x32_bf16(af[kt], bf, acc[fj], 0, 0, 0);
            }
        }
        // epilogue: s~ = cnorm - 2*dot; u64 top-2 insert per row-slot
#pragma unroll
        for (int fj = 0; fj < 8; ++fj) {
            const int code = code0 + ct * 128 + fj * 16 + l15;
            const float cn = cnorm[code];
#pragma unroll
            for (int reg = 0; reg < 4; ++reg) {
                const float sv = cn - 2.0f * acc[fj][reg];
                const u64 key = ((u64)mono_encode(sv) << 32) | (unsigned)code;
                if (key < p1[reg]) {
                    if (key < p0[reg]) { p1[reg] = p0[reg]; p0[reg] = key; }
                    else p1[reg] = key;
                }
            }
        }
    }
    // cross-lane (16-lane group, same kg => same rows) bitonic merge to top-4
#pragma unroll
    for (int rs = 0; rs < 4; ++rs) {
        u64 s0 = p0[rs], s1 = p1[rs], s2 = ~0ULL, s3 = ~0ULL;
#pragma unroll
        for (int m = 1; m < 16; m <<= 1) {
            u64 b0 = __shfl_xor(s0, m), b1 = __shfl_xor(s1, m);
            u64 b2 = __shfl_xor(s2, m), b3 = __shfl_xor(s3, m);
            u64 t0 = umin64(s0, b3), t1 = umin64(s1, b2);
            u64 t2 = umin64(s2, b1), t3 = umin64(s3, b0);
            u64 u0 = umin64(t0, t2), u2 = umax64(t0, t2);
            u64 u1 = umin64(t1, t3), u3 = umax64(t1, t3);
            s0 = umin64(u0, u1); s1 = umax64(u0, u1);
            s2 = umin64(u2, u3); s3 = umax64(u2, u3);
        }
        if (l15 == 0) {
            const int row = row0 + wid * 16 + kg * 4 + rs;
            t4[(size_t)(split * 4 + 0) * B_ROWS + row] = s0;
            t4[(size_t)(split * 4 + 1) * B_ROWS + row] = s1;
            t4[(size_t)(split * 4 + 2) * B_ROWS + row] = s2;
            t4[(size_t)(split * 4 + 3) * B_ROWS + row] = s3;
        }
    }
}

// ---------------------------------------------------------------------------
// candidate merge + EXACT rescore. v2: one thread per (row,slot) — 16
// threads/row, 4096 waves (16/CU) instead of 256 waves total. Per-candidate
// dot arithmetic BYTE-IDENTICAL to r11 (sequential fmaf, same k order, same
// final rounding chain). Selection = quarter-wave lexicographic (s,code)
// min reduce — order-independent, same result as r11's serial loop.
// Fused: count histogram + float index output.
// ---------------------------------------------------------------------------
__global__ void rescore_kernel(const float* __restrict__ z, const float* __restrict__ cb,
                               const float* __restrict__ cnorm, const float* __restrict__ znorm,
                               const u64* __restrict__ t4, int* __restrict__ indices,
                               int* __restrict__ counts, float* __restrict__ out_idx)
{
    const int gid  = blockIdx.x * 256 + threadIdx.x;
    const int row  = gid >> 4;
    const int slot = gid & 15;
    const u64 key = t4[(size_t)slot * B_ROWS + row];
    u64 kmin = key;
#pragma unroll
    for (int m = 1; m < 16; m <<= 1) kmin = umin64(kmin, __shfl_xor(kmin, m));
    const float thr = mono_decode((unsigned)(kmin >> 32)) + EPS_MARGIN;
    const float v   = mono_decode((unsigned)(key >> 32));
    const int  code = (int)(key & 0xFFFFFFFFu);
    float bs = 3.4028235e38f; int bi = 0x7FFFFFFF;
    if (v <= thr) {   // sentinel decodes to NaN -> excluded
        const float zn = znorm[row];
        const float* zp = &z[(size_t)row * DIM];
        const float* cp = &cb[(size_t)code * DIM];
        float acc = 0.f;
#pragma unroll 8
        for (int kk = 0; kk < DIM; ++kk) acc = fmaf(zp[kk], cp[kk], acc);
        const float t = __fsub_rn(zn, __fmul_rn(2.0f, acc));
        bs = __fadd_rn(t, cnorm[code]);
        bi = code;
    }
#pragma unroll
    for (int m = 1; m < 16; m <<= 1) {
        const float ov = __shfl_xor(bs, m);
        const int   oi = __shfl_xor(bi, m);
        if (ov < bs || (ov == bs && oi < bi)) { bs = ov; bi = oi; }
    }
    if (slot == 0) {
        indices[row] = bi;
        out_idx[row] = (float)bi;
        atomicAdd(&counts[bi], 1);
    }
}

// ---------------- downstream (unchanged, r9-validated) ----------------
__global__ void scan_kernel(const int* __restrict__ counts, int* __restrict__ offsets,
                            int* __restrict__ cursor) {
    const int lane = threadIdx.x;   // 64 lanes
    const int base = lane * 64;
    int s = 0;
    for (int i = 0; i < 64; ++i) s += counts[base + i];
    int v = s;
#pragma unroll
    for (int d = 1; d < 64; d <<= 1) {
        const int o = __shfl_up(v, d);
        if (lane >= d) v += o;
    }
    int run = v - s;
    for (int i = 0; i < 64; ++i) {
        const int c = counts[base + i];
        offsets[base + i] = run;
        cursor[base + i]  = run;
        run += c;
    }
}

__global__ void scatter_kernel(const int* __restrict__ idx, int* __restrict__ cursor,
                               int* __restrict__ buckets) {
    const int b = blockIdx.x * 256 + threadIdx.x;
    const int pos = atomicAdd(&cursor[idx[b]], 1);
    buckets[pos] = b;
}

__global__ void update_kernel(const float* __restrict__ z,
                              const float* __restrict__ ema_es, const float* __restrict__ ema_cs,
                              const int* __restrict__ counts, const int* __restrict__ offsets,
                              const int* __restrict__ buckets,
                              float* __restrict__ out_nes, float* __restrict__ out_ncs,
                              float* __restrict__ ws_ncs) {
    const int k = blockIdx.x;
    const int d = threadIdx.x;
    const int c = counts[k];
    const int o = offsets[k];
    float acc = 0.f;
    for (int j = 0; j < c; ++j) {
        const int r = buckets[o + j];
        acc += z[(size_t)r * DIM + d];
    }
    out_nes[(size_t)k * DIM + d] = 0.99f * ema_es[(size_t)k * DIM + d] + 0.01f * acc;
    if (d == 0) {
        const float ncs = 0.99f * ema_cs[k] + 0.01f * (float)c;
        out_ncs[k] = ncs;
        ws_ncs[k]  = ncs;
    }
}

__global__ void nsum_kernel(const float* __restrict__ ws_ncs, float* __restrict__ ws_n) {
    __shared__ float red[256];
    const int tid = threadIdx.x;
    float s = 0.f;
    for (int i = tid; i < K_CODES; i += 256) s += ws_ncs[i];
    red[tid] = s; __syncthreads();
    for (int st = 128; st > 0; st >>= 1) {
        if (tid < st) red[tid] += red[tid + st];
        __syncthreads();
    }
    if (tid == 0) ws_n[0] = red[0];
}

__global__ void codebook_kernel(const float* __restrict__ out_nes, const float* __restrict__ ws_ncs,
                                const float* __restrict__ ws_n, float* __restrict__ out_ncb) {
    const int k = blockIdx.x;
    const int d = threadIdx.x;
    const float n = ws_n[0];
    const float cs = (ws_ncs[k] + 1e-5f) / (n + (float)K_CODES * 1e-5f) * n;
    out_ncb[(size_t)k * DIM + d] = out_nes[(size_t)k * DIM + d] / cs;
}

__global__ void gather_loss_kernel(const float* __restrict__ z, const float* __restrict__ cb,
                                   const int* __restrict__ idx,
                                   float* __restrict__ out_zq, float* __restrict__ out_loss) {
    __shared__ float red[256];
    const int tid = threadIdx.x;
    float acc = 0.f;
    for (size_t i = blockIdx.x * 256 + tid; i < (size_t)B_ROWS * DIM; i += (size_t)gridDim.x * 256) {
        const int b = (int)(i >> 8);
        const int d = (int)(i & 255);
        const int k = idx[b];
        const float zq = cb[(size_t)k * DIM + d];
        const float ze = z[i];
        out_zq[i] = __fadd_rn(ze, __fsub_rn(zq, ze));
        const float diff = zq - ze;
        acc += diff * diff;
    }
    red[tid] = acc; __syncthreads();
    for (int st = 128; st > 0; st >>= 1) {
        if (tid < st) red[tid] += red[tid + st];
        __syncthreads();
    }
    if (tid == 0) atomicAdd(out_loss, red[0] * (0.25f / 4194304.0f));
}

extern "C" void kernel_launch(void* const* d_in, const int* in_sizes, int n_in,
                              void* d_out, int out_size, void* d_ws, size_t ws_size,
                              hipStream_t stream) {
    const float* z      = (const float*)d_in[0];
    const float* cb     = (const float*)d_in[1];
    const float* ema_cs = (const float*)d_in[2];
    const float* ema_es = (const float*)d_in[3];
    float* out = (float*)d_out;

    char* p = (char*)d_ws;
    u16*   zbf     = (u16*)p;   p += (size_t)B_ROWS * DIM * 2;   // 8 MB
    u16*   cbbf    = (u16*)p;   p += (size_t)K_CODES * DIM * 2;  // 2 MB
    u64*   t4      = (u64*)p;   p += (size_t)16 * B_ROWS * 8;    // 2 MB
    int*   indices = (int*)p;   p += B_ROWS * 4;
    int*   counts  = (int*)p;   p += K_CODES * 4;
    int*   offsets = (int*)p;   p += K_CODES * 4;
    int*   cursor  = (int*)p;   p += K_CODES * 4;
    int*   buckets = (int*)p;   p += B_ROWS * 4;
    float* cnorm   = (float*)p; p += K_CODES * 4;
    float* znorm   = (float*)p; p += B_ROWS * 4;
    float* ws_ncs  = (float*)p; p += K_CODES * 4;
    float* ws_n    = (float*)p; p += 256;

    hipMemsetAsync(counts, 0, K_CODES * 4, stream);
    hipMemsetAsync(out + OUT_LOSS, 0, 4, stream);

    zconv_kernel<<<(B_ROWS + 255) / 256, 256, 0, stream>>>(z, zbf, znorm);
    cconv_kernel<<<(K_CODES + 255) / 256, 256, 0, stream>>>(cb, cbbf, cnorm);
    score_kernel<<<(B_ROWS / 128) * 4, 512, 0, stream>>>(zbf, cbbf, cnorm, t4);
    rescore_kernel<<<(B_ROWS * 16) / 256, 256, 0, stream>>>(z, cb, cnorm, znorm, t4, indices,
                                                            counts, out + OUT_IDX);
    scan_kernel<<<1, 64, 0, stream>>>(counts, offsets, cursor);
    scatter_kernel<<<B_ROWS / 256, 256, 0, stream>>>(indices, cursor, buckets);
    update_kernel<<<K_CODES, 256, 0, stream>>>(z, ema_es, ema_cs, counts, offsets, buckets,
                                               out + OUT_NES, out + OUT_NCS, ws_ncs);
    nsum_kernel<<<1, 256, 0, stream>>>(ws_ncs, ws_n);
    codebook_kernel<<<K_CODES, 256, 0, stream>>>(out + OUT_NES, ws_ncs, ws_n, out + OUT_NCB);
    gather_loss_kernel<<<1024, 256, 0, stream>>>(z, cb, indices, out + OUT_ZQ, out + OUT_LOSS);
}